// Round 3
// baseline (153.314 us; speedup 1.0000x reference)
//
#include <hip/hip_runtime.h>
#include <math.h>

#define D_MODEL 768
#define HS 64
#define BATCH 8
#define SEQ 2048
#define SCALE 0.125f
#define KSPLIT 8
#define KCHUNK (SEQ / KSPLIT)   // 256
#define PM 32                   // proj M-tile
#define PN 96                   // proj N per block (2 blocks cover 192)

typedef _Float16 half_t;
typedef __attribute__((ext_vector_type(8))) _Float16 half8;
typedef __attribute__((ext_vector_type(4))) float floatx4;

// async global->LDS, 16B per lane, lane-linear LDS destination
typedef const __attribute__((address_space(1))) void gas_void;
typedef __attribute__((address_space(3))) void las_void;
__device__ __forceinline__ void gl_lds16(const void* g, void* l) {
    __builtin_amdgcn_global_load_lds((gas_void*)g, (las_void*)l, 16, 0, 0);
}
__device__ __forceinline__ void waitcnt_all() {
    __builtin_amdgcn_s_waitcnt(0);
}

// ---------------------------------------------------------------
// Kernel 1: W fp32 [D][H] x3 -> Wt fp16 [3*H][D]
// ---------------------------------------------------------------
__global__ __launch_bounds__(256)
void wconv_kernel(const float* __restrict__ Wq, const float* __restrict__ Wk,
                  const float* __restrict__ Wv, half_t* __restrict__ Wt)
{
    int m = blockIdx.x >> 6;
    int h = blockIdx.x & 63;
    const float* W = (m == 0) ? Wq : ((m == 1) ? Wk : Wv);
    half_t* dst = Wt + (size_t)blockIdx.x * D_MODEL;
    for (int k = threadIdx.x; k < D_MODEL; k += 256)
        dst[k] = (half_t)W[(size_t)k * HS + h];
}

// ---------------------------------------------------------------
// Kernel 2: QKV projection. M=32 x N=96 per block (grid 1024 ->
// 4 blocks/CU, 32 KB LDS, VGPR<=128 -> 4 waves/SIMD). Wave (msub,
// nsub) owns a 16x48 output sub-tile. Parity double-buffered LDS,
// one barrier/iter, register prefetch after the barrier.
// ---------------------------------------------------------------
__global__ __launch_bounds__(256, 4)
void proj_kernel(const float* __restrict__ x, const half_t* __restrict__ Wt,
                 const float* __restrict__ bq, const float* __restrict__ bk,
                 const float* __restrict__ bv,
                 half_t* __restrict__ Qh, half_t* __restrict__ Kh,
                 half_t* __restrict__ Vt)
{
    __shared__ __align__(16) half_t xs[2][PM * 64];    // 2 x 4 KB
    __shared__ __align__(16) half_t wtl[2][PN * 64];   // 2 x 12 KB

    const int tid = threadIdx.x;
    const int w = tid >> 6;
    const int lane = tid & 63;
    const int l15 = lane & 15;
    const int quad = lane >> 4;
    const int nhalf = blockIdx.x & 1;
    const long row0 = (long)(blockIdx.x >> 1) * PM;
    const int msub = w >> 1;          // 0..1 -> m rows msub*16..+16
    const int nsub = w & 1;           // 0..1 -> n cols nsub*48..+48

    floatx4 acc[3];
#pragma unroll
    for (int j = 0; j < 3; ++j) acc[j] = (floatx4){0.f, 0.f, 0.f, 0.f};

    float4 xA[2], xB[2];
    half8  wA[3], wB[3];

    auto loadx = [&](int k0, float4 (&v)[2]) {
        int r = tid >> 3, sc = tid & 7;
        int cg = sc ^ (r & 7);
        const float* p = x + (row0 + r) * D_MODEL + k0 + cg * 8;
        v[0] = *(const float4*)p;
        v[1] = *(const float4*)(p + 4);
    };
    auto loadw = [&](int k0, half8 (&wr)[3]) {
#pragma unroll
        for (int i = 0; i < 3; ++i) {
            int idx = i * 256 + tid;
            int r = idx >> 3, sc = idx & 7;
            int cg = sc ^ (r & 7);
            wr[i] = *(const half8*)(Wt + (size_t)(nhalf * PN + r) * D_MODEL + k0 + cg * 8);
        }
    };

    auto step = [&](int it, float4 (&xc)[2], half8 (&wc)[3],
                    float4 (&xn)[2], half8 (&wn)[3], int p) {
        // stage current tile into buf p (cvt x -> fp16 in regs)
        {
            float4 a = xc[0], b = xc[1];
            half8 xh = (half8){(half_t)a.x, (half_t)a.y, (half_t)a.z, (half_t)a.w,
                               (half_t)b.x, (half_t)b.y, (half_t)b.z, (half_t)b.w};
            *(half8*)&xs[p][tid * 8] = xh;
        }
#pragma unroll
        for (int i = 0; i < 3; ++i)
            *(half8*)&wtl[p][(i * 256 + tid) * 8] = wc[i];
        __syncthreads();                 // buf p staged across all waves
        // prefetch next tile AFTER barrier -> covered by the MFMA phase
        int kn = (it + 1 < 12) ? (it + 1) * 64 : 0;
        loadx(kn, xn);
        loadw(kn, wn);
        // compute from buf p
#pragma unroll
        for (int kst = 0; kst < 2; ++kst) {
            int ra = msub * 16 + l15;
            int slota = (kst * 4 + quad) ^ (ra & 7);
            half8 af = *(const half8*)&xs[p][ra * 64 + slota * 8];
#pragma unroll
            for (int nt = 0; nt < 3; ++nt) {
                int rb = nsub * 48 + nt * 16 + l15;
                int slotb = (kst * 4 + quad) ^ (rb & 7);
                half8 bf = *(const half8*)&wtl[p][rb * 64 + slotb * 8];
                acc[nt] = __builtin_amdgcn_mfma_f32_16x16x32_f16(
                    af, bf, acc[nt], 0, 0, 0);
            }
        }
    };

    loadx(0, xA);
    loadw(0, wA);
#pragma unroll
    for (int it = 0; it < 12; it += 2) {
        step(it,     xA, wA, xB, wB, 0);
        step(it + 1, xB, wB, xA, wA, 1);
    }

    // epilogue: bias + fp16 store (16-col tiles never straddle 64-boundaries)
#pragma unroll
    for (int nt = 0; nt < 3; ++nt) {
        int nbase = nhalf * PN + nsub * 48 + nt * 16;
        int mm = nbase >> 6;
        int h = (nbase + l15) & 63;
        const float* bias = (mm == 0) ? bq : ((mm == 1) ? bk : bv);
        float bval = bias[h];
#pragma unroll
        for (int r = 0; r < 4; ++r) {
            long R = row0 + msub * 16 + quad * 4 + r;
            half_t hv = (half_t)(acc[nt][r] + bval);
            if (mm == 0)      Qh[R * HS + h] = hv;
            else if (mm == 1) Kh[R * HS + h] = hv;
            else {
                long bb = R >> 11, s = R & 2047;
                Vt[(bb * HS + h) * SEQ + s] = hv;
            }
        }
    }
}

// ---------------------------------------------------------------
// Kernel 3: flash attention. 4-wave blocks (256 thr, 32 q/wave),
// grid (16,8,8)=1024. LDS 41 KB -> 3 blocks/CU = 12 waves/CU =
// 3 waves/SIMD; VGPR ~150 <= 170 cap (launch_bounds 256,3).
// K/V double-buffered, next tile's gl_lds issued under compute.
// ---------------------------------------------------------------
__global__ __launch_bounds__(256, 3)
void attn_kernel(const half_t* __restrict__ Qh, const half_t* __restrict__ Kh,
                 const half_t* __restrict__ Vt,
                 half_t* __restrict__ Opart, float* __restrict__ lpart)
{
    __shared__ __align__(16) half_t ks[2][64 * 64];   // 2 x 8 KB [kk][h] swizzled
    __shared__ __align__(16) half_t vs[2][64 * 64];   // 2 x 8 KB [h][kk] swizzled
    __shared__ __align__(16) half_t ps[4][16][72];    // 9 KB per-wave P

    const int tid = threadIdx.x;
    const int w = tid >> 6;
    const int lane = tid & 63;
    const int l15 = lane & 15;
    const int quad = lane >> 4;
    const int b = blockIdx.y;
    const int q0 = blockIdx.x * 128 + w * 32;
    const int kh = blockIdx.z;
    const int kk_begin = kh * KCHUNK;

    const half_t* Kb = Kh + (size_t)b * SEQ * HS;
    const half_t* Vb = Vt + (size_t)b * HS * SEQ;

    half8 qf[2][2];
#pragma unroll
    for (int mt = 0; mt < 2; ++mt)
#pragma unroll
        for (int kst = 0; kst < 2; ++kst) {
            half8 q = *(const half8*)(Qh + ((size_t)b * SEQ + q0 + mt * 16 + l15) * HS
                                      + kst * 32 + quad * 8);
#pragma unroll
            for (int j = 0; j < 8; ++j) q[j] = q[j] * (half_t)SCALE;
            qf[mt][kst] = q;
        }

    floatx4 oacc[2][4];
    float lsum[2][4];
#pragma unroll
    for (int mt = 0; mt < 2; ++mt) {
#pragma unroll
        for (int nt = 0; nt < 4; ++nt) oacc[mt][nt] = (floatx4){0.f, 0.f, 0.f, 0.f};
#pragma unroll
        for (int r = 0; r < 4; ++r) lsum[mt][r] = 0.f;
    }

    // stage K + V^T tile into buf p: 512+512 half8-chunks, 256 threads
    auto stage = [&](int p, int kk0) {
#pragma unroll
        for (int i = 0; i < 2; ++i) {
            int idx = i * 256 + tid;
            int r = idx >> 3, sc = idx & 7;
            int cg = sc ^ (r & 7);
            gl_lds16(Kb + (size_t)(kk0 + r) * HS + cg * 8, &ks[p][idx * 8]);
            gl_lds16(Vb + (size_t)r * SEQ + kk0 + cg * 8, &vs[p][idx * 8]);
        }
    };

    stage(0, kk_begin);                    // prologue: tile 0 in flight

    for (int it = 0; it < KCHUNK / 64; ++it) {
        const int cur = it & 1;
        waitcnt_all();     // this thread's async LDS writes landed
        __syncthreads();   // tile visible; WAR fence for buf cur^1
        if (it + 1 < KCHUNK / 64)
            stage(cur ^ 1, kk_begin + (it + 1) * 64);   // flies under compute

        // V-fragments into registers once per tile
        half8 vf[4][2];
#pragma unroll
        for (int nt = 0; nt < 4; ++nt)
#pragma unroll
            for (int kst = 0; kst < 2; ++kst) {
                int r = nt * 16 + l15;
                int slot = (kst * 4 + quad) ^ (r & 7);
                vf[nt][kst] = *(const half8*)&vs[cur][r * 64 + slot * 8];
            }

        // QK^T for both 16-row m-tiles
        floatx4 sacc[2][4];
#pragma unroll
        for (int mt = 0; mt < 2; ++mt)
#pragma unroll
            for (int nt = 0; nt < 4; ++nt) sacc[mt][nt] = (floatx4){0.f, 0.f, 0.f, 0.f};
#pragma unroll
        for (int nt = 0; nt < 4; ++nt)
#pragma unroll
            for (int kst = 0; kst < 2; ++kst) {
                int r = nt * 16 + l15;
                int slot = (kst * 4 + quad) ^ (r & 7);
                half8 kf = *(const half8*)&ks[cur][r * 64 + slot * 8];
#pragma unroll
                for (int mt = 0; mt < 2; ++mt)
                    sacc[mt][nt] = __builtin_amdgcn_mfma_f32_16x16x32_f16(
                        qf[mt][kst], kf, sacc[mt][nt], 0, 0, 0);
            }

        // softmax numerator + PV per m-tile (P bounced through LDS)
#pragma unroll
        for (int mt = 0; mt < 2; ++mt) {
#pragma unroll
            for (int nt = 0; nt < 4; ++nt)
#pragma unroll
                for (int r = 0; r < 4; ++r) {
                    float pv = __expf(sacc[mt][nt][r]);
                    lsum[mt][r] += pv;
                    ps[w][quad * 4 + r][nt * 16 + l15] = (half_t)pv;
                }
            half8 pfr[2];
#pragma unroll
            for (int kst = 0; kst < 2; ++kst)
                pfr[kst] = *(const half8*)&ps[w][l15][kst * 32 + quad * 8];
#pragma unroll
            for (int nt = 0; nt < 4; ++nt)
#pragma unroll
                for (int kst = 0; kst < 2; ++kst)
                    oacc[mt][nt] = __builtin_amdgcn_mfma_f32_16x16x32_f16(
                        pfr[kst], vf[nt][kst], oacc[mt][nt], 0, 0, 0);
        }
    }

    // reduce l across the 16 column-lanes of each quad
#pragma unroll
    for (int mt = 0; mt < 2; ++mt)
#pragma unroll
        for (int r = 0; r < 4; ++r) {
            float s = lsum[mt][r];
            s += __shfl_xor(s, 1);
            s += __shfl_xor(s, 2);
            s += __shfl_xor(s, 4);
            s += __shfl_xor(s, 8);
            lsum[mt][r] = s;
        }

    size_t obase = ((size_t)kh * BATCH + b) * SEQ * HS;
#pragma unroll
    for (int mt = 0; mt < 2; ++mt)
#pragma unroll
        for (int nt = 0; nt < 4; ++nt)
#pragma unroll
            for (int r = 0; r < 4; ++r) {
                int row = q0 + mt * 16 + quad * 4 + r;
                Opart[obase + (size_t)row * HS + nt * 16 + l15] = (half_t)oacc[mt][nt][r];
            }
    if (l15 == 0) {
#pragma unroll
        for (int mt = 0; mt < 2; ++mt)
#pragma unroll
            for (int r = 0; r < 4; ++r) {
                int row = q0 + mt * 16 + quad * 4 + r;
                lpart[((size_t)kh * BATCH + b) * SEQ + row] = lsum[mt][r];
            }
    }
}

// ---------------------------------------------------------------
// Kernel 4: combine KSPLIT partials: out = sum(O_i) / sum(l_i)
// ---------------------------------------------------------------
__global__ __launch_bounds__(256)
void combine_kernel(const half_t* __restrict__ Opart, const float* __restrict__ lpart,
                    float* __restrict__ out)
{
    const size_t NT = (size_t)BATCH * SEQ * HS;
    const size_t BS = (size_t)BATCH * SEQ;
    size_t e0 = ((size_t)blockIdx.x * 256 + threadIdx.x) * 8;
    size_t row = e0 / HS;
    float o[8] = {0, 0, 0, 0, 0, 0, 0, 0};
    float l = 0.f;
#pragma unroll
    for (int i = 0; i < KSPLIT; ++i) {
        half8 oi = *(const half8*)(Opart + (size_t)i * NT + e0);
#pragma unroll
        for (int j = 0; j < 8; ++j) o[j] += (float)oi[j];
        l += lpart[(size_t)i * BS + row];
    }
    float inv = 1.f / l;
    float4 a = {o[0] * inv, o[1] * inv, o[2] * inv, o[3] * inv};
    float4 c = {o[4] * inv, o[5] * inv, o[6] * inv, o[7] * inv};
    *(float4*)(out + e0) = a;
    *(float4*)(out + e0 + 4) = c;
}

extern "C" void kernel_launch(void* const* d_in, const int* in_sizes, int n_in,
                              void* d_out, int out_size, void* d_ws, size_t ws_size,
                              hipStream_t stream) {
    const float* x  = (const float*)d_in[0];
    const float* Wq = (const float*)d_in[1];
    const float* bq = (const float*)d_in[2];
    const float* Wk = (const float*)d_in[3];
    const float* bk = (const float*)d_in[4];
    const float* Wv = (const float*)d_in[5];
    const float* bv = (const float*)d_in[6];
    float* out = (float*)d_out;

    const size_t per = (size_t)BATCH * SEQ * HS;      // 1,048,576 elements
    half_t* Qh = (half_t*)d_ws;
    half_t* Kh = Qh + per;
    half_t* Vt = Kh + per;
    half_t* Wt = Vt + per;                            // 147,456 halfs
    half_t* Opart = Wt + 3 * HS * D_MODEL;
    float*  lpart = (float*)(Opart + (size_t)KSPLIT * per);   // ~23 MB total

    wconv_kernel<<<dim3(3 * HS), dim3(256), 0, stream>>>(Wq, Wk, Wv, Wt);
    proj_kernel<<<dim3((BATCH * SEQ / PM) * 2), dim3(256), 0, stream>>>(
        x, Wt, bq, bk, bv, Qh, Kh, Vt);
    attn_kernel<<<dim3(SEQ / 128, BATCH, KSPLIT), dim3(256), 0, stream>>>(
        Qh, Kh, Vt, Opart, lpart);
    combine_kernel<<<dim3((BATCH * SEQ * HS) / (256 * 8)), dim3(256), 0, stream>>>(
        Opart, lpart, out);
}

// Round 5
// 137.604 us; speedup vs baseline: 1.1142x; 1.1142x over previous
//
#include <hip/hip_runtime.h>
#include <math.h>

#define D_MODEL 768
#define HS 64
#define BATCH 8
#define SEQ 2048
// Q is pre-scaled by 0.125*log2(e) in proj's epilogue (fp32), so attn
// computes P = 2^(Qs . K) with a single v_exp_f32 and no extra muls.
#define QSCALE_LOG2E 0.1803368801f
#define KSPLIT 8
#define KCHUNK (SEQ / KSPLIT)   // 256
#define PM 32                   // proj M-tile -> grid 512

typedef _Float16 half_t;
typedef __attribute__((ext_vector_type(8))) _Float16 half8;
typedef __attribute__((ext_vector_type(4))) float floatx4;

// async global->LDS, 16B per lane, lane-linear LDS destination
typedef const __attribute__((address_space(1))) void gas_void;
typedef __attribute__((address_space(3))) void las_void;
__device__ __forceinline__ void gl_lds16(const void* g, void* l) {
    __builtin_amdgcn_global_load_lds((gas_void*)g, (las_void*)l, 16, 0, 0);
}
__device__ __forceinline__ void waitcnt_all() {
    __builtin_amdgcn_s_waitcnt(0);
}
__device__ __forceinline__ float fast_exp2(float x) {
#if __has_builtin(__builtin_amdgcn_exp2f)
    return __builtin_amdgcn_exp2f(x);
#else
    return exp2f(x);
#endif
}

// ---------------------------------------------------------------
// Kernel 1: W fp32 [D][H] x3 -> Wt fp16 [3*H][D], via coalesced
// 64x64 LDS transpose (old version read fp32 at stride 256B = 16x
// read amplification). Grid 36 = 3 matrices x 12 k-tiles.
// ---------------------------------------------------------------
__global__ __launch_bounds__(256)
void wconv_kernel(const float* __restrict__ Wq, const float* __restrict__ Wk,
                  const float* __restrict__ Wv, half_t* __restrict__ Wt)
{
    __shared__ float lds[64][65];
    const int m = blockIdx.x / 12;
    const int k0 = (blockIdx.x % 12) * 64;
    const float* W = (m == 0) ? Wq : ((m == 1) ? Wk : Wv);
    const int tid = threadIdx.x;
#pragma unroll
    for (int ri = 0; ri < 4; ++ri) {
        int row = ri * 16 + (tid >> 4);
        int col = (tid & 15) * 4;
        float4 v = *(const float4*)(W + (size_t)(k0 + row) * HS + col);
        lds[row][col] = v.x; lds[row][col + 1] = v.y;
        lds[row][col + 2] = v.z; lds[row][col + 3] = v.w;
    }
    __syncthreads();
#pragma unroll
    for (int i = 0; i < 2; ++i) {
        int idx = i * 256 + tid;
        int h = idx >> 3;
        int kc = idx & 7;
        half8 o;
#pragma unroll
        for (int j = 0; j < 8; ++j) o[j] = (half_t)lds[kc * 8 + j][h];
        *(half8*)(Wt + (size_t)(m * HS + h) * D_MODEL + k0 + kc * 8) = o;
    }
}

// ---------------------------------------------------------------
// Kernel 2: QKV projection. M=32 x N=192 tile (grid 512), parity
// double-buffered LDS, ONE barrier/iter, register prefetch after
// the barrier. Q rows pre-scaled by 0.125*log2e (fp32) so attn's
// softmax is a bare v_exp_f32.
// ---------------------------------------------------------------
__global__ __launch_bounds__(256)
void proj_kernel(const float* __restrict__ x, const half_t* __restrict__ Wt,
                 const float* __restrict__ bq, const float* __restrict__ bk,
                 const float* __restrict__ bv,
                 half_t* __restrict__ Qh, half_t* __restrict__ Kh,
                 half_t* __restrict__ Vt)
{
    __shared__ __align__(16) half_t xs[2][PM * 64];    // 2 x 4 KB
    __shared__ __align__(16) half_t wtl[2][192 * 64];  // 2 x 24 KB

    const int tid = threadIdx.x;
    const int w = tid >> 6;
    const int lane = tid & 63;
    const int l15 = lane & 15;
    const int quad = lane >> 4;
    const long row0 = (long)blockIdx.x * PM;

    floatx4 acc[2][3];
#pragma unroll
    for (int i = 0; i < 2; ++i)
#pragma unroll
        for (int j = 0; j < 3; ++j) acc[i][j] = (floatx4){0.f, 0.f, 0.f, 0.f};

    float4 xA[2], xB[2];
    half8  wA[6], wB[6];

    auto loadx = [&](int k0, float4 (&v)[2]) {
        int r = tid >> 3, sc = tid & 7;
        int cg = sc ^ (r & 7);
        const float* p = x + (row0 + r) * D_MODEL + k0 + cg * 8;
        v[0] = *(const float4*)p;
        v[1] = *(const float4*)(p + 4);
    };
    auto loadw = [&](int k0, half8 (&wr)[6]) {
#pragma unroll
        for (int i = 0; i < 6; ++i) {
            int idx = i * 256 + tid;
            int r = idx >> 3, sc = idx & 7;
            int cg = sc ^ (r & 7);
            wr[i] = *(const half8*)(Wt + (size_t)r * D_MODEL + k0 + cg * 8);
        }
    };

    auto step = [&](int it, float4 (&xc)[2], half8 (&wc)[6],
                    float4 (&xn)[2], half8 (&wn)[6], int p) {
        {
            float4 a = xc[0], b = xc[1];
            half8 xh = (half8){(half_t)a.x, (half_t)a.y, (half_t)a.z, (half_t)a.w,
                               (half_t)b.x, (half_t)b.y, (half_t)b.z, (half_t)b.w};
            *(half8*)&xs[p][tid * 8] = xh;
        }
#pragma unroll
        for (int i = 0; i < 6; ++i)
            *(half8*)&wtl[p][(i * 256 + tid) * 8] = wc[i];
        __syncthreads();                 // buf p staged across all waves
        // prefetch next tile AFTER barrier -> covered by the MFMA phase
        int kn = (it + 1 < 12) ? (it + 1) * 64 : 0;
        loadx(kn, xn);
        loadw(kn, wn);
#pragma unroll
        for (int kst = 0; kst < 2; ++kst) {
            half8 af[2];
#pragma unroll
            for (int mt = 0; mt < 2; ++mt) {
                int r = mt * 16 + l15;
                int slot = (kst * 4 + quad) ^ (r & 7);
                af[mt] = *(const half8*)&xs[p][r * 64 + slot * 8];
            }
#pragma unroll
            for (int nt = 0; nt < 3; ++nt) {
                int r = w * 48 + nt * 16 + l15;
                int slot = (kst * 4 + quad) ^ (r & 7);
                half8 bf = *(const half8*)&wtl[p][r * 64 + slot * 8];
#pragma unroll
                for (int mt = 0; mt < 2; ++mt)
                    acc[mt][nt] = __builtin_amdgcn_mfma_f32_16x16x32_f16(
                        af[mt], bf, acc[mt][nt], 0, 0, 0);
            }
        }
    };

    loadx(0, xA);
    loadw(0, wA);
#pragma unroll
    for (int it = 0; it < 12; it += 2) {
        step(it,     xA, wA, xB, wB, 0);
        step(it + 1, xB, wB, xA, wA, 1);
    }

    // epilogue: bias (+ Q pre-scale) + fp16 store
#pragma unroll
    for (int nt = 0; nt < 3; ++nt) {
        int nbase = w * 48 + nt * 16;
        int mm = nbase >> 6;
        int h = (nbase + l15) & 63;
        const float* bias = (mm == 0) ? bq : ((mm == 1) ? bk : bv);
        float bval = bias[h];
#pragma unroll
        for (int mt = 0; mt < 2; ++mt)
#pragma unroll
            for (int r = 0; r < 4; ++r) {
                long R = row0 + mt * 16 + quad * 4 + r;
                float fv = acc[mt][nt][r] + bval;
                if (mm == 0) {
                    Qh[R * HS + h] = (half_t)(fv * QSCALE_LOG2E);
                } else if (mm == 1) {
                    Kh[R * HS + h] = (half_t)fv;
                } else {
                    long bb = R >> 11, s = R & 2047;
                    Vt[(bb * HS + h) * SEQ + s] = (half_t)fv;
                }
            }
    }
}

// ---------------------------------------------------------------
// Kernel 3: flash attention. 2-wave blocks (128 thr, 64 q/wave),
// grid (16,8,8)=1024 -> 4 blocks/CU (LDS 36.5K), 2 waves/SIMD
// (register-pinned). K/V double-buffered: next tile's gl_lds
// issued right after current tile's visibility barrier. setprio
// around MFMA clusters (T5 regime: independent blocks per CU).
// ---------------------------------------------------------------
__global__ __launch_bounds__(128)
void attn_kernel(const half_t* __restrict__ Qh, const half_t* __restrict__ Kh,
                 const half_t* __restrict__ Vt,
                 half_t* __restrict__ Opart, float* __restrict__ lpart)
{
    __shared__ __align__(16) half_t ks[2][64 * 64];   // 2 x 8 KB [kk][h] swizzled
    __shared__ __align__(16) half_t vs[2][64 * 64];   // 2 x 8 KB [h][kk] swizzled
    __shared__ __align__(16) half_t ps[2][16][72];    // 4.5 KB per-wave P

    const int tid = threadIdx.x;
    const int w = tid >> 6;
    const int lane = tid & 63;
    const int l15 = lane & 15;
    const int quad = lane >> 4;
    const int b = blockIdx.y;
    const int q0 = blockIdx.x * 128 + w * 64;
    const int kh = blockIdx.z;
    const int kk_begin = kh * KCHUNK;

    const half_t* Kb = Kh + (size_t)b * SEQ * HS;
    const half_t* Vb = Vt + (size_t)b * HS * SEQ;

    half8 qf[4][2];
#pragma unroll
    for (int mt = 0; mt < 4; ++mt)
#pragma unroll
        for (int kst = 0; kst < 2; ++kst)
            qf[mt][kst] = *(const half8*)(Qh + ((size_t)b * SEQ + q0 + mt * 16 + l15) * HS
                                          + kst * 32 + quad * 8);

    floatx4 oacc[4][4];
    float lsum[4][4];
#pragma unroll
    for (int mt = 0; mt < 4; ++mt) {
#pragma unroll
        for (int nt = 0; nt < 4; ++nt) oacc[mt][nt] = (floatx4){0.f, 0.f, 0.f, 0.f};
#pragma unroll
        for (int r = 0; r < 4; ++r) lsum[mt][r] = 0.f;
    }

    // stage K + V^T tile into buf p: 512+512 half8-chunks (4+4 gl_lds/thread)
    auto stage = [&](int p, int kk0) {
#pragma unroll
        for (int i = 0; i < 4; ++i) {
            int idx = i * 128 + tid;
            int r = idx >> 3, sc = idx & 7;
            int cg = sc ^ (r & 7);
            gl_lds16(Kb + (size_t)(kk0 + r) * HS + cg * 8, &ks[p][idx * 8]);
            gl_lds16(Vb + (size_t)r * SEQ + kk0 + cg * 8, &vs[p][idx * 8]);
        }
    };

    stage(0, kk_begin);                    // prologue: tile 0 in flight

    for (int it = 0; it < KCHUNK / 64; ++it) {
        const int cur = it & 1;
        waitcnt_all();     // this thread's async LDS writes landed
        __syncthreads();   // tile visible; WAR fence for buf cur^1
        if (it + 1 < KCHUNK / 64)
            stage(cur ^ 1, kk_begin + (it + 1) * 64);   // flies under compute

        // V-fragments into registers once per tile
        half8 vf[4][2];
#pragma unroll
        for (int nt = 0; nt < 4; ++nt)
#pragma unroll
            for (int kst = 0; kst < 2; ++kst) {
                int r = nt * 16 + l15;
                int slot = (kst * 4 + quad) ^ (r & 7);
                vf[nt][kst] = *(const half8*)&vs[cur][r * 64 + slot * 8];
            }

#pragma unroll
        for (int h2 = 0; h2 < 2; ++h2) {
            floatx4 sacc[2][4];
#pragma unroll
            for (int mtl = 0; mtl < 2; ++mtl)
#pragma unroll
                for (int nt = 0; nt < 4; ++nt) sacc[mtl][nt] = (floatx4){0.f, 0.f, 0.f, 0.f};
            __builtin_amdgcn_s_setprio(1);
#pragma unroll
            for (int nt = 0; nt < 4; ++nt)
#pragma unroll
                for (int kst = 0; kst < 2; ++kst) {
                    int r = nt * 16 + l15;
                    int slot = (kst * 4 + quad) ^ (r & 7);
                    half8 kf = *(const half8*)&ks[cur][r * 64 + slot * 8];
#pragma unroll
                    for (int mtl = 0; mtl < 2; ++mtl)
                        sacc[mtl][nt] = __builtin_amdgcn_mfma_f32_16x16x32_f16(
                            qf[h2 * 2 + mtl][kst], kf, sacc[mtl][nt], 0, 0, 0);
                }
            __builtin_amdgcn_s_setprio(0);

#pragma unroll
            for (int mtl = 0; mtl < 2; ++mtl) {
                int mt = h2 * 2 + mtl;
#pragma unroll
                for (int nt = 0; nt < 4; ++nt)
#pragma unroll
                    for (int r = 0; r < 4; ++r) {
                        float pv = fast_exp2(sacc[mtl][nt][r]);   // Q pre-scaled
                        lsum[mt][r] += pv;
                        ps[w][quad * 4 + r][nt * 16 + l15] = (half_t)pv;
                    }
                half8 pfr[2];
#pragma unroll
                for (int kst = 0; kst < 2; ++kst)
                    pfr[kst] = *(const half8*)&ps[w][l15][kst * 32 + quad * 8];
                __builtin_amdgcn_s_setprio(1);
#pragma unroll
                for (int nt = 0; nt < 4; ++nt)
#pragma unroll
                    for (int kst = 0; kst < 2; ++kst)
                        oacc[mt][nt] = __builtin_amdgcn_mfma_f32_16x16x32_f16(
                            pfr[kst], vf[nt][kst], oacc[mt][nt], 0, 0, 0);
                __builtin_amdgcn_s_setprio(0);
            }
        }
    }

    // reduce l across the 16 column-lanes of each quad
#pragma unroll
    for (int mt = 0; mt < 4; ++mt)
#pragma unroll
        for (int r = 0; r < 4; ++r) {
            float s = lsum[mt][r];
            s += __shfl_xor(s, 1);
            s += __shfl_xor(s, 2);
            s += __shfl_xor(s, 4);
            s += __shfl_xor(s, 8);
            lsum[mt][r] = s;
        }

    size_t obase = ((size_t)kh * BATCH + b) * SEQ * HS;
#pragma unroll
    for (int mt = 0; mt < 4; ++mt)
#pragma unroll
        for (int nt = 0; nt < 4; ++nt)
#pragma unroll
            for (int r = 0; r < 4; ++r) {
                int row = q0 + mt * 16 + quad * 4 + r;
                Opart[obase + (size_t)row * HS + nt * 16 + l15] = (half_t)oacc[mt][nt][r];
            }
    if (l15 == 0) {
#pragma unroll
        for (int mt = 0; mt < 4; ++mt)
#pragma unroll
            for (int r = 0; r < 4; ++r) {
                int row = q0 + mt * 16 + quad * 4 + r;
                lpart[((size_t)kh * BATCH + b) * SEQ + row] = lsum[mt][r];
            }
    }
}

// ---------------------------------------------------------------
// Kernel 4: combine KSPLIT partials: out = sum(O_i) / sum(l_i)
// ---------------------------------------------------------------
__global__ __launch_bounds__(256)
void combine_kernel(const half_t* __restrict__ Opart, const float* __restrict__ lpart,
                    float* __restrict__ out)
{
    const size_t NT = (size_t)BATCH * SEQ * HS;
    const size_t BS = (size_t)BATCH * SEQ;
    size_t e0 = ((size_t)blockIdx.x * 256 + threadIdx.x) * 8;
    size_t row = e0 / HS;
    float o[8] = {0, 0, 0, 0, 0, 0, 0, 0};
    float l = 0.f;
#pragma unroll
    for (int i = 0; i < KSPLIT; ++i) {
        half8 oi = *(const half8*)(Opart + (size_t)i * NT + e0);
#pragma unroll
        for (int j = 0; j < 8; ++j) o[j] += (float)oi[j];
        l += lpart[(size_t)i * BS + row];
    }
    float inv = 1.f / l;
    float4 a = {o[0] * inv, o[1] * inv, o[2] * inv, o[3] * inv};
    float4 c = {o[4] * inv, o[5] * inv, o[6] * inv, o[7] * inv};
    *(float4*)(out + e0) = a;
    *(float4*)(out + e0 + 4) = c;
}

extern "C" void kernel_launch(void* const* d_in, const int* in_sizes, int n_in,
                              void* d_out, int out_size, void* d_ws, size_t ws_size,
                              hipStream_t stream) {
    const float* x  = (const float*)d_in[0];
    const float* Wq = (const float*)d_in[1];
    const float* bq = (const float*)d_in[2];
    const float* Wk = (const float*)d_in[3];
    const float* bk = (const float*)d_in[4];
    const float* Wv = (const float*)d_in[5];
    const float* bv = (const float*)d_in[6];
    float* out = (float*)d_out;

    const size_t per = (size_t)BATCH * SEQ * HS;      // 1,048,576 elements
    half_t* Qh = (half_t*)d_ws;
    half_t* Kh = Qh + per;
    half_t* Vt = Kh + per;
    half_t* Wt = Vt + per;                            // 147,456 halfs
    half_t* Opart = Wt + 3 * HS * D_MODEL;
    float*  lpart = (float*)(Opart + (size_t)KSPLIT * per);   // ~23 MB total

    wconv_kernel<<<dim3(36), dim3(256), 0, stream>>>(Wq, Wk, Wv, Wt);
    proj_kernel<<<dim3(BATCH * SEQ / PM), dim3(256), 0, stream>>>(
        x, Wt, bq, bk, bv, Qh, Kh, Vt);
    attn_kernel<<<dim3(SEQ / 128, BATCH, KSPLIT), dim3(128), 0, stream>>>(
        Qh, Kh, Vt, Opart, lpart);
    combine_kernel<<<dim3((BATCH * SEQ * HS) / (256 * 8)), dim3(256), 0, stream>>>(
        Opart, lpart, out);
}

// Round 6
// 134.358 us; speedup vs baseline: 1.1411x; 1.0242x over previous
//
#include <hip/hip_runtime.h>
#include <math.h>

#define D_MODEL 768
#define HS 64
#define BATCH 8
#define SEQ 2048
// Q is pre-scaled by 0.125*log2(e) in proj's epilogue (fp32), so attn
// computes P = 2^(Qs . K) with a single v_exp_f32 and no extra muls.
#define QSCALE_LOG2E 0.1803368801f
#define KSPLIT 8
#define KCHUNK (SEQ / KSPLIT)   // 256
#define PM 32                   // proj M-tile -> grid 512

typedef _Float16 half_t;
typedef __attribute__((ext_vector_type(8))) _Float16 half8;
typedef __attribute__((ext_vector_type(4))) float floatx4;

// async global->LDS, 16B per lane, lane-linear LDS destination
typedef const __attribute__((address_space(1))) void gas_void;
typedef __attribute__((address_space(3))) void las_void;
__device__ __forceinline__ void gl_lds16(const void* g, void* l) {
    __builtin_amdgcn_global_load_lds((gas_void*)g, (las_void*)l, 16, 0, 0);
}
__device__ __forceinline__ void waitcnt_all() {
    __builtin_amdgcn_s_waitcnt(0);
}
__device__ __forceinline__ float fast_exp2(float x) {
#if __has_builtin(__builtin_amdgcn_exp2f)
    return __builtin_amdgcn_exp2f(x);
#else
    return exp2f(x);
#endif
}

// ---------------------------------------------------------------
// Kernel 1: W fp32 [D][H] x3 -> Wt fp16 [3*H][D], via coalesced
// 64x64 LDS transpose. Grid 36 = 3 matrices x 12 k-tiles.
// ---------------------------------------------------------------
__global__ __launch_bounds__(256)
void wconv_kernel(const float* __restrict__ Wq, const float* __restrict__ Wk,
                  const float* __restrict__ Wv, half_t* __restrict__ Wt)
{
    __shared__ float lds[64][65];
    const int m = blockIdx.x / 12;
    const int k0 = (blockIdx.x % 12) * 64;
    const float* W = (m == 0) ? Wq : ((m == 1) ? Wk : Wv);
    const int tid = threadIdx.x;
#pragma unroll
    for (int ri = 0; ri < 4; ++ri) {
        int row = ri * 16 + (tid >> 4);
        int col = (tid & 15) * 4;
        float4 v = *(const float4*)(W + (size_t)(k0 + row) * HS + col);
        lds[row][col] = v.x; lds[row][col + 1] = v.y;
        lds[row][col + 2] = v.z; lds[row][col + 3] = v.w;
    }
    __syncthreads();
#pragma unroll
    for (int i = 0; i < 2; ++i) {
        int idx = i * 256 + tid;
        int h = idx >> 3;
        int kc = idx & 7;
        half8 o;
#pragma unroll
        for (int j = 0; j < 8; ++j) o[j] = (half_t)lds[kc * 8 + j][h];
        *(half8*)(Wt + (size_t)(m * HS + h) * D_MODEL + k0 + kc * 8) = o;
    }
}

// ---------------------------------------------------------------
// Kernel 2: QKV projection. M=32 x N=192 tile (grid 512), parity
// double-buffered LDS, ONE barrier/iter, register prefetch after
// the barrier. Q rows pre-scaled by 0.125*log2e (fp32).
// ---------------------------------------------------------------
__global__ __launch_bounds__(256)
void proj_kernel(const float* __restrict__ x, const half_t* __restrict__ Wt,
                 const float* __restrict__ bq, const float* __restrict__ bk,
                 const float* __restrict__ bv,
                 half_t* __restrict__ Qh, half_t* __restrict__ Kh,
                 half_t* __restrict__ Vt)
{
    __shared__ __align__(16) half_t xs[2][PM * 64];    // 2 x 4 KB
    __shared__ __align__(16) half_t wtl[2][192 * 64];  // 2 x 24 KB

    const int tid = threadIdx.x;
    const int w = tid >> 6;
    const int lane = tid & 63;
    const int l15 = lane & 15;
    const int quad = lane >> 4;
    const long row0 = (long)blockIdx.x * PM;

    floatx4 acc[2][3];
#pragma unroll
    for (int i = 0; i < 2; ++i)
#pragma unroll
        for (int j = 0; j < 3; ++j) acc[i][j] = (floatx4){0.f, 0.f, 0.f, 0.f};

    float4 xA[2], xB[2];
    half8  wA[6], wB[6];

    auto loadx = [&](int k0, float4 (&v)[2]) {
        int r = tid >> 3, sc = tid & 7;
        int cg = sc ^ (r & 7);
        const float* p = x + (row0 + r) * D_MODEL + k0 + cg * 8;
        v[0] = *(const float4*)p;
        v[1] = *(const float4*)(p + 4);
    };
    auto loadw = [&](int k0, half8 (&wr)[6]) {
#pragma unroll
        for (int i = 0; i < 6; ++i) {
            int idx = i * 256 + tid;
            int r = idx >> 3, sc = idx & 7;
            int cg = sc ^ (r & 7);
            wr[i] = *(const half8*)(Wt + (size_t)r * D_MODEL + k0 + cg * 8);
        }
    };

    auto step = [&](int it, float4 (&xc)[2], half8 (&wc)[6],
                    float4 (&xn)[2], half8 (&wn)[6], int p) {
        {
            float4 a = xc[0], b = xc[1];
            half8 xh = (half8){(half_t)a.x, (half_t)a.y, (half_t)a.z, (half_t)a.w,
                               (half_t)b.x, (half_t)b.y, (half_t)b.z, (half_t)b.w};
            *(half8*)&xs[p][tid * 8] = xh;
        }
#pragma unroll
        for (int i = 0; i < 6; ++i)
            *(half8*)&wtl[p][(i * 256 + tid) * 8] = wc[i];
        __syncthreads();                 // buf p staged across all waves
        // prefetch next tile AFTER barrier -> covered by the MFMA phase
        int kn = (it + 1 < 12) ? (it + 1) * 64 : 0;
        loadx(kn, xn);
        loadw(kn, wn);
#pragma unroll
        for (int kst = 0; kst < 2; ++kst) {
            half8 af[2];
#pragma unroll
            for (int mt = 0; mt < 2; ++mt) {
                int r = mt * 16 + l15;
                int slot = (kst * 4 + quad) ^ (r & 7);
                af[mt] = *(const half8*)&xs[p][r * 64 + slot * 8];
            }
#pragma unroll
            for (int nt = 0; nt < 3; ++nt) {
                int r = w * 48 + nt * 16 + l15;
                int slot = (kst * 4 + quad) ^ (r & 7);
                half8 bf = *(const half8*)&wtl[p][r * 64 + slot * 8];
#pragma unroll
                for (int mt = 0; mt < 2; ++mt)
                    acc[mt][nt] = __builtin_amdgcn_mfma_f32_16x16x32_f16(
                        af[mt], bf, acc[mt][nt], 0, 0, 0);
            }
        }
    };

    loadx(0, xA);
    loadw(0, wA);
#pragma unroll
    for (int it = 0; it < 12; it += 2) {
        step(it,     xA, wA, xB, wB, 0);
        step(it + 1, xB, wB, xA, wA, 1);
    }

    // epilogue: bias (+ Q pre-scale) + fp16 store
#pragma unroll
    for (int nt = 0; nt < 3; ++nt) {
        int nbase = w * 48 + nt * 16;
        int mm = nbase >> 6;
        int h = (nbase + l15) & 63;
        const float* bias = (mm == 0) ? bq : ((mm == 1) ? bk : bv);
        float bval = bias[h];
#pragma unroll
        for (int mt = 0; mt < 2; ++mt)
#pragma unroll
            for (int r = 0; r < 4; ++r) {
                long R = row0 + mt * 16 + quad * 4 + r;
                float fv = acc[mt][nt][r] + bval;
                if (mm == 0) {
                    Qh[R * HS + h] = (half_t)(fv * QSCALE_LOG2E);
                } else if (mm == 1) {
                    Kh[R * HS + h] = (half_t)fv;
                } else {
                    long bb = R >> 11, s = R & 2047;
                    Vt[(bb * HS + h) * SEQ + s] = (half_t)fv;
                }
            }
    }
}

// ---------------------------------------------------------------
// Kernel 3: flash attention. 2-wave blocks (128 thr, 64 q/wave),
// grid (16,8,8)=1024. K double-buffered via gl_lds; V read DIRECT
// from global into registers (V chunk is 32KB/(b,kh), L2-resident,
// reused by 16 q-blocks — staging it was pure overhead, m169 /
// common-mistake #7). setprio REMOVED (m190: null-to-negative for
// barrier-lockstep waves; R5 regression suspect). LDS 20.9 KB.
// ---------------------------------------------------------------
__global__ __launch_bounds__(128)
void attn_kernel(const half_t* __restrict__ Qh, const half_t* __restrict__ Kh,
                 const half_t* __restrict__ Vt,
                 half_t* __restrict__ Opart, float* __restrict__ lpart)
{
    __shared__ __align__(16) half_t ks[2][64 * 64];   // 2 x 8 KB [kk][h] swizzled
    __shared__ __align__(16) half_t ps[2][16][72];    // 4.5 KB per-wave P

    const int tid = threadIdx.x;
    const int w = tid >> 6;
    const int lane = tid & 63;
    const int l15 = lane & 15;
    const int quad = lane >> 4;
    const int b = blockIdx.y;
    const int q0 = blockIdx.x * 128 + w * 64;
    const int kh = blockIdx.z;
    const int kk_begin = kh * KCHUNK;

    const half_t* Kb = Kh + (size_t)b * SEQ * HS;
    const half_t* Vb = Vt + (size_t)b * HS * SEQ;

    // stage K tile into buf p: 512 half8-chunks (4 gl_lds/thread)
    auto stage = [&](int p, int kk0) {
#pragma unroll
        for (int i = 0; i < 4; ++i) {
            int idx = i * 128 + tid;
            int r = idx >> 3, sc = idx & 7;
            int cg = sc ^ (r & 7);
            gl_lds16(Kb + (size_t)(kk0 + r) * HS + cg * 8, &ks[p][idx * 8]);
        }
    };

    stage(0, kk_begin);                    // K tile 0 in flight first

    half8 qf[4][2];
#pragma unroll
    for (int mt = 0; mt < 4; ++mt)
#pragma unroll
        for (int kst = 0; kst < 2; ++kst)
            qf[mt][kst] = *(const half8*)(Qh + ((size_t)b * SEQ + q0 + mt * 16 + l15) * HS
                                          + kst * 32 + quad * 8);

    floatx4 oacc[4][4];
    float lsum[4][4];
#pragma unroll
    for (int mt = 0; mt < 4; ++mt) {
#pragma unroll
        for (int nt = 0; nt < 4; ++nt) oacc[mt][nt] = (floatx4){0.f, 0.f, 0.f, 0.f};
#pragma unroll
        for (int r = 0; r < 4; ++r) lsum[mt][r] = 0.f;
    }

    for (int it = 0; it < KCHUNK / 64; ++it) {
        const int cur = it & 1;
        const int kk0 = kk_begin + it * 64;
        waitcnt_all();     // this thread's async K writes landed
        __syncthreads();   // tile visible; WAR fence for buf cur^1
        if (it + 1 < KCHUNK / 64)
            stage(cur ^ 1, kk0 + 64);      // next K tile flies under compute

        // V-fragments direct from global (L2-hit), issued early so the
        // QK^T + softmax phase hides their latency
        half8 vf[4][2];
#pragma unroll
        for (int nt = 0; nt < 4; ++nt)
#pragma unroll
            for (int kst = 0; kst < 2; ++kst)
                vf[nt][kst] = *(const half8*)(Vb + (size_t)(nt * 16 + l15) * SEQ
                                              + kk0 + kst * 32 + quad * 8);

#pragma unroll
        for (int h2 = 0; h2 < 2; ++h2) {
            floatx4 sacc[2][4];
#pragma unroll
            for (int mtl = 0; mtl < 2; ++mtl)
#pragma unroll
                for (int nt = 0; nt < 4; ++nt) sacc[mtl][nt] = (floatx4){0.f, 0.f, 0.f, 0.f};
#pragma unroll
            for (int nt = 0; nt < 4; ++nt)
#pragma unroll
                for (int kst = 0; kst < 2; ++kst) {
                    int r = nt * 16 + l15;
                    int slot = (kst * 4 + quad) ^ (r & 7);
                    half8 kf = *(const half8*)&ks[cur][r * 64 + slot * 8];
#pragma unroll
                    for (int mtl = 0; mtl < 2; ++mtl)
                        sacc[mtl][nt] = __builtin_amdgcn_mfma_f32_16x16x32_f16(
                            qf[h2 * 2 + mtl][kst], kf, sacc[mtl][nt], 0, 0, 0);
                }

#pragma unroll
            for (int mtl = 0; mtl < 2; ++mtl) {
                int mt = h2 * 2 + mtl;
#pragma unroll
                for (int nt = 0; nt < 4; ++nt)
#pragma unroll
                    for (int r = 0; r < 4; ++r) {
                        float pv = fast_exp2(sacc[mtl][nt][r]);   // Q pre-scaled
                        lsum[mt][r] += pv;
                        ps[w][quad * 4 + r][nt * 16 + l15] = (half_t)pv;
                    }
                half8 pfr[2];
#pragma unroll
                for (int kst = 0; kst < 2; ++kst)
                    pfr[kst] = *(const half8*)&ps[w][l15][kst * 32 + quad * 8];
#pragma unroll
                for (int nt = 0; nt < 4; ++nt)
#pragma unroll
                    for (int kst = 0; kst < 2; ++kst)
                        oacc[mt][nt] = __builtin_amdgcn_mfma_f32_16x16x32_f16(
                            pfr[kst], vf[nt][kst], oacc[mt][nt], 0, 0, 0);
            }
        }
    }

    // reduce l across the 16 column-lanes of each quad
#pragma unroll
    for (int mt = 0; mt < 4; ++mt)
#pragma unroll
        for (int r = 0; r < 4; ++r) {
            float s = lsum[mt][r];
            s += __shfl_xor(s, 1);
            s += __shfl_xor(s, 2);
            s += __shfl_xor(s, 4);
            s += __shfl_xor(s, 8);
            lsum[mt][r] = s;
        }

    size_t obase = ((size_t)kh * BATCH + b) * SEQ * HS;
#pragma unroll
    for (int mt = 0; mt < 4; ++mt)
#pragma unroll
        for (int nt = 0; nt < 4; ++nt)
#pragma unroll
            for (int r = 0; r < 4; ++r) {
                int row = q0 + mt * 16 + quad * 4 + r;
                Opart[obase + (size_t)row * HS + nt * 16 + l15] = (half_t)oacc[mt][nt][r];
            }
    if (l15 == 0) {
#pragma unroll
        for (int mt = 0; mt < 4; ++mt)
#pragma unroll
            for (int r = 0; r < 4; ++r) {
                int row = q0 + mt * 16 + quad * 4 + r;
                lpart[((size_t)kh * BATCH + b) * SEQ + row] = lsum[mt][r];
            }
    }
}

// ---------------------------------------------------------------
// Kernel 4: combine KSPLIT partials: out = sum(O_i) / sum(l_i)
// ---------------------------------------------------------------
__global__ __launch_bounds__(256)
void combine_kernel(const half_t* __restrict__ Opart, const float* __restrict__ lpart,
                    float* __restrict__ out)
{
    const size_t NT = (size_t)BATCH * SEQ * HS;
    const size_t BS = (size_t)BATCH * SEQ;
    size_t e0 = ((size_t)blockIdx.x * 256 + threadIdx.x) * 8;
    size_t row = e0 / HS;
    float o[8] = {0, 0, 0, 0, 0, 0, 0, 0};
    float l = 0.f;
#pragma unroll
    for (int i = 0; i < KSPLIT; ++i) {
        half8 oi = *(const half8*)(Opart + (size_t)i * NT + e0);
#pragma unroll
        for (int j = 0; j < 8; ++j) o[j] += (float)oi[j];
        l += lpart[(size_t)i * BS + row];
    }
    float inv = 1.f / l;
    float4 a = {o[0] * inv, o[1] * inv, o[2] * inv, o[3] * inv};
    float4 c = {o[4] * inv, o[5] * inv, o[6] * inv, o[7] * inv};
    *(float4*)(out + e0) = a;
    *(float4*)(out + e0 + 4) = c;
}

extern "C" void kernel_launch(void* const* d_in, const int* in_sizes, int n_in,
                              void* d_out, int out_size, void* d_ws, size_t ws_size,
                              hipStream_t stream) {
    const float* x  = (const float*)d_in[0];
    const float* Wq = (const float*)d_in[1];
    const float* bq = (const float*)d_in[2];
    const float* Wk = (const float*)d_in[3];
    const float* bk = (const float*)d_in[4];
    const float* Wv = (const float*)d_in[5];
    const float* bv = (const float*)d_in[6];
    float* out = (float*)d_out;

    const size_t per = (size_t)BATCH * SEQ * HS;      // 1,048,576 elements
    half_t* Qh = (half_t*)d_ws;
    half_t* Kh = Qh + per;
    half_t* Vt = Kh + per;
    half_t* Wt = Vt + per;                            // 147,456 halfs
    half_t* Opart = Wt + 3 * HS * D_MODEL;
    float*  lpart = (float*)(Opart + (size_t)KSPLIT * per);   // ~23 MB total

    wconv_kernel<<<dim3(36), dim3(256), 0, stream>>>(Wq, Wk, Wv, Wt);
    proj_kernel<<<dim3(BATCH * SEQ / PM), dim3(256), 0, stream>>>(
        x, Wt, bq, bk, bv, Qh, Kh, Vt);
    attn_kernel<<<dim3(SEQ / 128, BATCH, KSPLIT), dim3(128), 0, stream>>>(
        Qh, Kh, Vt, Opart, lpart);
    combine_kernel<<<dim3((BATCH * SEQ * HS) / (256 * 8)), dim3(256), 0, stream>>>(
        Opart, lpart, out);
}